// Round 5
// baseline (11142.016 us; speedup 1.0000x reference)
//
#include <hip/hip_runtime.h>

#define T_LEN 2048
#define G_N   24
#define V_N   2048
#define K_N   512
#define NCL   48          // 24 groups x 2 directions
#define NBLK  96          // 2 workgroups (column halves) per chain

// ---------------- workspace layout (bytes) ----------------
#define FLAGS_OFF  0
#define TOK_OFF    4096
#define ROWS_OFF   16384
#define HBUF_OFF   262144     // 48 cl x 2 ws x 2 bufs x 256 f32 = 384 KB
#define P_OFF      786432     // 4 MB

#define LOAD_RLX(p)     __hip_atomic_load((p), __ATOMIC_RELAXED, __HIP_MEMORY_SCOPE_AGENT)
#define STORE_RLX(p, v) __hip_atomic_store((p), (v), __ATOMIC_RELAXED, __HIP_MEMORY_SCOPE_AGENT)

// ---- phase 0: recover tokens from one-hot rows ----
__global__ void tok_kernel(const float* __restrict__ seq, int* __restrict__ tokens) {
    int wid  = (blockIdx.x * blockDim.x + threadIdx.x) >> 6;
    int lane = threadIdx.x & 63;
    if (wid >= T_LEN) return;
    const float* row = seq + (size_t)wid * V_N;
    for (int i = lane; i < V_N; i += 64) {
        if (row[i] > 0.5f) tokens[wid] = i;
    }
}

// ---- phase 1: rows[g][t] = perms[g][token[t]] ----
__global__ void rows_kernel(const int* __restrict__ tokens, const int* __restrict__ perms,
                            int* __restrict__ rows) {
    int idx = blockIdx.x * blockDim.x + threadIdx.x;
    if (idx >= G_N * T_LEN) return;
    int g = idx / T_LEN, t = idx - g * T_LEN;
    rows[idx] = perms[g * V_N + tokens[t]];
}

// ---- phase 2: P = W_e @ Wx + b ----
__global__ __launch_bounds__(256) void pgemm_kernel(const float* __restrict__ We,
                                                    const float* __restrict__ Wx,
                                                    const float* __restrict__ b,
                                                    float* __restrict__ P) {
    __shared__ float As[16][72];
    __shared__ float Bs[16][68];
    int tid = threadIdx.x;
    int bx = blockIdx.x & 7;
    int by = blockIdx.x >> 3;
    int tx = tid & 15, ty = tid >> 4;
    int v0 = by * 64, j0 = bx * 64;
    float acc[4][4] = {};
    for (int k0 = 0; k0 < K_N; k0 += 16) {
        int ar = tid >> 2;
        int ac = (tid & 3) << 2;
        float4 av = *(const float4*)(We + (size_t)(v0 + ar) * K_N + k0 + ac);
        As[ac + 0][ar] = av.x; As[ac + 1][ar] = av.y;
        As[ac + 2][ar] = av.z; As[ac + 3][ar] = av.w;
        int br = tid >> 4;
        int bc = (tid & 15) << 2;
        float4 bv = *(const float4*)(Wx + (size_t)(k0 + br) * K_N + j0 + bc);
        *(float4*)&Bs[br][bc] = bv;
        __syncthreads();
#pragma unroll
        for (int kk = 0; kk < 16; kk++) {
            float a0 = As[kk][ty * 4 + 0], a1 = As[kk][ty * 4 + 1];
            float a2 = As[kk][ty * 4 + 2], a3 = As[kk][ty * 4 + 3];
            float4 bb = *(const float4*)&Bs[kk][tx * 4];
            acc[0][0] += a0 * bb.x; acc[0][1] += a0 * bb.y; acc[0][2] += a0 * bb.z; acc[0][3] += a0 * bb.w;
            acc[1][0] += a1 * bb.x; acc[1][1] += a1 * bb.y; acc[1][2] += a1 * bb.z; acc[1][3] += a1 * bb.w;
            acc[2][0] += a2 * bb.x; acc[2][1] += a2 * bb.y; acc[2][2] += a2 * bb.z; acc[2][3] += a2 * bb.w;
            acc[3][0] += a3 * bb.x; acc[3][1] += a3 * bb.y; acc[3][2] += a3 * bb.z; acc[3][3] += a3 * bb.w;
        }
        __syncthreads();
    }
    float4 bb = *(const float4*)(b + j0 + tx * 4);
#pragma unroll
    for (int i = 0; i < 4; i++) {
        float4 r;
        r.x = acc[i][0] + bb.x; r.y = acc[i][1] + bb.y;
        r.z = acc[i][2] + bb.z; r.w = acc[i][3] + bb.w;
        *(float4*)(P + (size_t)(v0 + ty * 4 + i) * K_N + j0 + tx * 4) = r;
    }
}

// ---- phase 3: 2-WG-per-chain COLUMN-split RNN, weights fully on-chip ----
// 96 blocks x 512 threads; block = (g, dir, ws). WG ws owns columns
// j in [256ws, 256ws+256) over ALL 512 k-rows: 512 KB of Wh = 128 KB LDS
// + 192 "VGPR" (compiler splits 128 arch + AGPR overflow; AGPRs are direct
// VALU operands on gfx950 -> cheap). Exchange payload is h itself (1 KB
// each way, half of R4's partials) and the tanh/reduce is done once per
// column (no redundant work).
// Overlap (the R4->R5 lever): each thread's 64 k-rows = 32 own-half +
// 32 partner-half. FMA1 over own-half rows (h available locally) runs
// while the partner's h half is in flight from the LLC; FMA2 consumes it
// after one barrier. Exchange latency hides under FMA1.
// Protocol: relaxed agent-scope (sc1) data stores/loads + release-flag /
// all-thread relaxed poll + acquire fence (proven R0/R4). Ping-pong bufs.
// pr padded to stride 264 so ds_read2-paired reduce reads are 8 banks
// apart (R4's 25M conflict cycles -> ~0).
__global__ __attribute__((amdgpu_flat_work_group_size(512, 512), amdgpu_waves_per_eu(2, 2)))
void rnn_pair(const float* __restrict__ P, const float* __restrict__ Wh,
              const int* __restrict__ rows, float* __restrict__ h_buf,
              int* __restrict__ flags, float* __restrict__ out) {

    __shared__ __align__(16) float  lds_h[K_N];          // 2 KB, full h
    __shared__ __align__(16) float4 Wlds[16 * 512];      // 128 KB: [ph*8+row][tid]
    __shared__ __align__(16) float  pr[8 * 264];         // 8.25 KB padded

    const int tid = threadIdx.x;
    const int q   = tid >> 6;          // wave id: k-subslice (32+32 rows)
    const int c   = tid & 63;          // col group: local cols 4c..4c+3
    const int cluster = blockIdx.x >> 1;
    const int ws  = blockIdx.x & 1;    // column half
    const int g   = cluster >> 1;
    const int dir = cluster & 1;

    const int ownbase = ws << 8;             // my 256 columns AND "my" k-half
    const int pbase   = ownbase ^ 256;       // partner half
    const int wcol    = (ws << 6) + c;       // f4 column index into Wh row

    const float4* __restrict__ Wh4 = (const float4*)Wh;

    // weight fill: phase 0 = own-half k rows, phase 1 = partner-half k rows.
    // rows 0..7 of each 32-row slice -> LDS, rows 8..31 -> registers.
    float4 Wreg[48];
#pragma unroll
    for (int ph = 0; ph < 2; ph++) {
        const int kb = (ph == 0 ? ownbase : pbase) + (q << 5);
#pragma unroll
        for (int i = 0; i < 32; i++) {
            float4 w = Wh4[(size_t)(kb + i) * 128 + wcol];
            if (i < 8) Wlds[(ph * 8 + i) * 512 + tid] = w;
            else       Wreg[ph * 24 + (i - 8)] = w;
        }
    }
    lds_h[tid] = 0.f;                        // h_0 = 0 (both halves)

    const int* __restrict__ myrows = rows + g * T_LEN;
    int t0 = (dir == 0) ? 0 : (T_LEN - 2);
    float xv = (tid < 256) ? P[(size_t)myrows[t0] * K_N + ownbase + tid] : 0.f;
    int t1 = (dir == 0) ? 1 : (T_LEN - 3);
    int rnxt = myrows[t1];

    int* myflag = flags + cluster * 2 + ws;
    int* pflag  = flags + cluster * 2 + (ws ^ 1);
    float* hbme = h_buf + ((size_t)cluster * 2 + ws) * 512;         // 2 bufs x 256
    float* hbpt = h_buf + ((size_t)cluster * 2 + (ws ^ 1)) * 512;

    const size_t outbase = (size_t)g * 1024 + (size_t)dir * 512 + ownbase + tid;
    float h_prev = 0.f;
    size_t prev_addr = 0;

    __syncthreads();

    for (int s = 0; s < T_LEN; s++) {
        // staggered out-store of h computed last step: drains under compute
        if (s > 0 && tid < 256) __builtin_nontemporal_store(h_prev, &out[prev_addr]);
        // x prefetch for s+1; row index for s+2
        float xv_next = 0.f;
        if (tid < 256 && s + 1 < T_LEN) xv_next = P[(size_t)rnxt * K_N + ownbase + tid];
        if (s + 2 < T_LEN) {
            int sn = s + 2;
            int tn = (dir == 0) ? sn : ((sn == T_LEN - 1) ? (T_LEN - 1) : (T_LEN - 2 - sn));
            rnxt = myrows[tn];
        }

        // ---- poll partner flag + issue partner-h load (overlaps FMA1) ----
        float pv = 0.f;
        if (s > 0) {
            while (LOAD_RLX(pflag) < s) { }
            __builtin_amdgcn_fence(__ATOMIC_ACQUIRE, "workgroup");
            if (tid < 256) pv = LOAD_RLX(&hbpt[(s & 1) * 256 + tid]);
        }

        const float4* __restrict__ h4 = (const float4*)lds_h;
        float4 acc = {0.f, 0.f, 0.f, 0.f};

        // ---- FMA1: 32 own-half rows (h local since end of prev step) ----
        {
            const int hb = (ownbase >> 2) + (q << 3);
#pragma unroll
            for (int r8 = 0; r8 < 8; r8++) {
                float4 hv = h4[hb + r8];                 // uniform -> broadcast
#pragma unroll
                for (int e = 0; e < 4; e++) {
                    float hs = (e == 0) ? hv.x : (e == 1) ? hv.y : (e == 2) ? hv.z : hv.w;
                    const int i = 4 * r8 + e;
                    float4 w = (i < 8) ? Wlds[i * 512 + tid] : Wreg[i - 8];
                    acc.x += hs * w.x; acc.y += hs * w.y; acc.z += hs * w.z; acc.w += hs * w.w;
                }
            }
        }
        // publish partner h half to LDS (waitcnt lands here, mostly drained)
        if (s > 0 && tid < 256) lds_h[pbase + tid] = pv;
        __syncthreads();                               // A

        // ---- FMA2: 32 partner-half rows ----
        {
            const int hb = (pbase >> 2) + (q << 3);
#pragma unroll
            for (int r8 = 0; r8 < 8; r8++) {
                float4 hv = h4[hb + r8];
#pragma unroll
                for (int e = 0; e < 4; e++) {
                    float hs = (e == 0) ? hv.x : (e == 1) ? hv.y : (e == 2) ? hv.z : hv.w;
                    const int i = 4 * r8 + e;
                    float4 w = (i < 8) ? Wlds[(8 + i) * 512 + tid] : Wreg[24 + i - 8];
                    acc.x += hs * w.x; acc.y += hs * w.y; acc.z += hs * w.z; acc.w += hs * w.w;
                }
            }
        }
        *(float4*)&pr[q * 264 + 4 * c] = acc;          // contiguous f4, conflict-free
        __syncthreads();                               // B

        // ---- reduce 8 wave-partials, tanh, publish (tid<256: col = tid) ----
        if (tid < 256) {
            float p0 = pr[0 * 264 + tid], p1 = pr[1 * 264 + tid];
            float p2 = pr[2 * 264 + tid], p3 = pr[3 * 264 + tid];
            float p4 = pr[4 * 264 + tid], p5 = pr[5 * 264 + tid];
            float p6 = pr[6 * 264 + tid], p7 = pr[7 * 264 + tid];
            float sum = ((p0 + p1) + (p2 + p3)) + ((p4 + p5) + (p6 + p7));
            float z = xv + sum;
            z = fminf(15.f, fmaxf(-15.f, z));
            float e2 = __expf(2.f * z);
            float h1 = 1.f - 2.f / (e2 + 1.f);         // tanh(z)
            xv = xv_next;

            int tphys = (dir == 0) ? s : ((s == T_LEN - 1) ? (T_LEN - 1) : (T_LEN - 2 - s));
            prev_addr = (size_t)tphys * (G_N * 1024) + outbase;
            h_prev = h1;
            if (s < T_LEN - 1) {
                STORE_RLX(&hbme[((s + 1) & 1) * 256 + tid], h1);   // sc1 -> LLC
                lds_h[ownbase + tid] = h1;                          // own half local
            }
        }
        if (s == T_LEN - 1) break;
        __syncthreads();                               // C: drains hbme stores + LDS
        if (tid == 0)
            __hip_atomic_store(myflag, s + 1, __ATOMIC_RELEASE, __HIP_MEMORY_SCOPE_AGENT);
    }
    if (tid < 256) {
        __builtin_nontemporal_store(h_prev, &out[prev_addr]);
        __builtin_nontemporal_store(h_prev, &out[(size_t)T_LEN * (G_N * 1024) + outbase]);
    }
}

extern "C" void kernel_launch(void* const* d_in, const int* in_sizes, int n_in,
                              void* d_out, int out_size, void* d_ws, size_t ws_size,
                              hipStream_t stream) {
    const float* seq   = (const float*)d_in[0];
    const int*   perms = (const int*)d_in[1];
    const float* We    = (const float*)d_in[2];
    const float* Wx    = (const float*)d_in[3];
    const float* Wh    = (const float*)d_in[4];
    const float* b     = (const float*)d_in[5];
    float* out = (float*)d_out;
    char* ws = (char*)d_ws;

    int*   flags  = (int*)(ws + FLAGS_OFF);
    int*   tokens = (int*)(ws + TOK_OFF);
    int*   rows   = (int*)(ws + ROWS_OFF);
    float* hbuf   = (float*)(ws + HBUF_OFF);
    float* P      = (float*)(ws + P_OFF);

    (void)hipMemsetAsync(flags, 0, NCL * 2 * sizeof(int), stream);
    tok_kernel<<<512, 256, 0, stream>>>(seq, tokens);
    rows_kernel<<<(G_N * T_LEN + 255) / 256, 256, 0, stream>>>(tokens, perms, rows);
    pgemm_kernel<<<256, 256, 0, stream>>>(We, Wx, b, P);
    rnn_pair<<<NBLK, 512, 0, stream>>>(P, Wh, rows, hbuf, flags, out);
}

// Round 6
// 5771.534 us; speedup vs baseline: 1.9305x; 1.9305x over previous
//
#include <hip/hip_runtime.h>

#define T_LEN 2048
#define G_N   24
#define V_N   2048
#define K_N   512
#define NCL   48          // 24 groups x 2 directions
#define NBLK  96          // 2 workgroups (column halves) per chain

// ---------------- workspace layout (bytes) ----------------
#define TOK_OFF    4096
#define ROWS_OFF   16384
#define HBUF_OFF   262144     // 48 cl x 2 ws x 2 bufs x 256 x 8B = 384 KB
#define P_OFF      786432     // 4 MB

#define LOAD_RLX64(p)     __hip_atomic_load((p), __ATOMIC_RELAXED, __HIP_MEMORY_SCOPE_AGENT)
#define STORE_RLX64(p, v) __hip_atomic_store((p), (v), __ATOMIC_RELAXED, __HIP_MEMORY_SCOPE_AGENT)

// LDS-visibility barrier WITHOUT the __syncthreads vmcnt(0) drain:
// writer-side lgkmcnt(0) then s_barrier (standard semantics), with compiler
// memory fences so no LDS op is scheduled across it (rule #18).
#define BAR_LDS() do {                                         \
    asm volatile("s_waitcnt lgkmcnt(0)" ::: "memory");         \
    __builtin_amdgcn_s_barrier();                              \
    asm volatile("" ::: "memory");                             \
} while (0)

// ---- phase 0: recover tokens from one-hot rows ----
__global__ void tok_kernel(const float* __restrict__ seq, int* __restrict__ tokens) {
    int wid  = (blockIdx.x * blockDim.x + threadIdx.x) >> 6;
    int lane = threadIdx.x & 63;
    if (wid >= T_LEN) return;
    const float* row = seq + (size_t)wid * V_N;
    for (int i = lane; i < V_N; i += 64) {
        if (row[i] > 0.5f) tokens[wid] = i;
    }
}

// ---- phase 1: rows[g][t] = perms[g][token[t]] ----
__global__ void rows_kernel(const int* __restrict__ tokens, const int* __restrict__ perms,
                            int* __restrict__ rows) {
    int idx = blockIdx.x * blockDim.x + threadIdx.x;
    if (idx >= G_N * T_LEN) return;
    int g = idx / T_LEN, t = idx - g * T_LEN;
    rows[idx] = perms[g * V_N + tokens[t]];
}

// ---- phase 2: P = W_e @ Wx + b ----
__global__ __launch_bounds__(256) void pgemm_kernel(const float* __restrict__ We,
                                                    const float* __restrict__ Wx,
                                                    const float* __restrict__ b,
                                                    float* __restrict__ P) {
    __shared__ float As[16][72];
    __shared__ float Bs[16][68];
    int tid = threadIdx.x;
    int bx = blockIdx.x & 7;
    int by = blockIdx.x >> 3;
    int tx = tid & 15, ty = tid >> 4;
    int v0 = by * 64, j0 = bx * 64;
    float acc[4][4] = {};
    for (int k0 = 0; k0 < K_N; k0 += 16) {
        int ar = tid >> 2;
        int ac = (tid & 3) << 2;
        float4 av = *(const float4*)(We + (size_t)(v0 + ar) * K_N + k0 + ac);
        As[ac + 0][ar] = av.x; As[ac + 1][ar] = av.y;
        As[ac + 2][ar] = av.z; As[ac + 3][ar] = av.w;
        int br = tid >> 4;
        int bc = (tid & 15) << 2;
        float4 bv = *(const float4*)(Wx + (size_t)(k0 + br) * K_N + j0 + bc);
        *(float4*)&Bs[br][bc] = bv;
        __syncthreads();
#pragma unroll
        for (int kk = 0; kk < 16; kk++) {
            float a0 = As[kk][ty * 4 + 0], a1 = As[kk][ty * 4 + 1];
            float a2 = As[kk][ty * 4 + 2], a3 = As[kk][ty * 4 + 3];
            float4 bb = *(const float4*)&Bs[kk][tx * 4];
            acc[0][0] += a0 * bb.x; acc[0][1] += a0 * bb.y; acc[0][2] += a0 * bb.z; acc[0][3] += a0 * bb.w;
            acc[1][0] += a1 * bb.x; acc[1][1] += a1 * bb.y; acc[1][2] += a1 * bb.z; acc[1][3] += a1 * bb.w;
            acc[2][0] += a2 * bb.x; acc[2][1] += a2 * bb.y; acc[2][2] += a2 * bb.z; acc[2][3] += a2 * bb.w;
            acc[3][0] += a3 * bb.x; acc[3][1] += a3 * bb.y; acc[3][2] += a3 * bb.z; acc[3][3] += a3 * bb.w;
        }
        __syncthreads();
    }
    float4 bb = *(const float4*)(b + j0 + tx * 4);
#pragma unroll
    for (int i = 0; i < 4; i++) {
        float4 r;
        r.x = acc[i][0] + bb.x; r.y = acc[i][1] + bb.y;
        r.z = acc[i][2] + bb.z; r.w = acc[i][3] + bb.w;
        *(float4*)(P + (size_t)(v0 + ty * 4 + i) * K_N + j0 + tx * 4) = r;
    }
}

// ---- phase 3: 2-WG-per-chain column-split RNN, tagged-exchange ----
// Structure as R5 (ws owns 256 columns over all 512 k-rows; 128 KB LDS +
// 192-reg weights; FMA1 own-half rows / FMA2 partner-half rows), with the
// R5->R6 protocol fix:
//  * h exchange = ONE relaxed agent-scope 8B store per element packing
//    {tag = s+1, h bits}. The data store IS the signal: no producer
//    vmcnt drain, no release flag, no flag round-trip. Consumer issues the
//    tagged load at step top, tag-checks after FMA1 (latency hidden),
//    retries only if the partner lags. Ping-pong + monotone tags make
//    overwrite-before-read impossible (producer can be at most 1 step
//    ahead via the recurrence dependency). hbuf memset per launch ->
//    stale tags never match (tags start at 1).
//  * all in-loop barriers are lgkmcnt-only (BAR_LDS): __syncthreads would
//    drain vmcnt(0), serializing out-stores/h-stores/prefetches (the R5
//    regression); here they free-run.
__global__ __attribute__((amdgpu_flat_work_group_size(512, 512), amdgpu_waves_per_eu(2, 2)))
void rnn_pair(const float* __restrict__ P, const float* __restrict__ Wh,
              const int* __restrict__ rows, unsigned long long* __restrict__ h_buf,
              float* __restrict__ out) {

    __shared__ __align__(16) float  lds_h[K_N];          // 2 KB, full h
    __shared__ __align__(16) float4 Wlds[16 * 512];      // 128 KB: [ph*8+row][tid]
    __shared__ __align__(16) float  pr[8 * 264];         // 8.25 KB padded

    const int tid = threadIdx.x;
    const int q   = tid >> 6;          // wave id: k-subslice (32 own + 32 partner rows)
    const int cluster = blockIdx.x >> 1;
    const int ws  = blockIdx.x & 1;    // column half
    const int g   = cluster >> 1;
    const int dir = cluster & 1;

    const int ownbase = ws << 8;             // my 256 columns AND "my" k-half
    const int pbase   = ownbase ^ 256;       // partner half
    const int wcol    = (ws << 6) + (tid & 63);  // f4 column index into Wh row

    const float4* __restrict__ Wh4 = (const float4*)Wh;

    // weight fill: phase 0 = own-half k rows, phase 1 = partner-half k rows.
    // rows 0..7 of each 32-row slice -> LDS, rows 8..31 -> registers/AGPRs.
    float4 Wreg[48];
#pragma unroll
    for (int ph = 0; ph < 2; ph++) {
        const int kb = (ph == 0 ? ownbase : pbase) + (q << 5);
#pragma unroll
        for (int i = 0; i < 32; i++) {
            float4 w = Wh4[(size_t)(kb + i) * 128 + wcol];
            if (i < 8) Wlds[(ph * 8 + i) * 512 + tid] = w;
            else       Wreg[ph * 24 + (i - 8)] = w;
        }
    }
    lds_h[tid] = 0.f;                        // h_0 = 0 (both halves)

    const int* __restrict__ myrows = rows + g * T_LEN;
    int t0 = (dir == 0) ? 0 : (T_LEN - 2);
    float xv = (tid < 256) ? P[(size_t)myrows[t0] * K_N + ownbase + tid] : 0.f;
    int t1 = (dir == 0) ? 1 : (T_LEN - 3);
    int rnxt = myrows[t1];

    unsigned long long* hbme = h_buf + ((size_t)cluster * 2 + ws) * 512;        // 2 bufs x 256
    unsigned long long* hbpt = h_buf + ((size_t)cluster * 2 + (ws ^ 1)) * 512;

    const size_t outbase = (size_t)g * 1024 + (size_t)dir * 512 + ownbase + tid;
    float h_prev = 0.f;
    size_t prev_addr = 0;

    __syncthreads();   // one-time: weights + h0 visible (full drain OK here)

    for (int s = 0; s < T_LEN; s++) {
        // ---- issue partner-h tagged load FIRST (resolves after FMA1) ----
        unsigned long long pvbits = 0;
        if (s > 0 && tid < 256)
            pvbits = LOAD_RLX64(&hbpt[((s - 1) & 1) * 256 + tid]);

        // staggered out-store of h(s-1): fire-and-forget (no drain until used)
        if (s > 0 && tid < 256) __builtin_nontemporal_store(h_prev, &out[prev_addr]);
        // x prefetch for s+1; row index for s+2
        float xv_next = 0.f;
        if (tid < 256 && s + 1 < T_LEN) xv_next = P[(size_t)rnxt * K_N + ownbase + tid];
        if (s + 2 < T_LEN) {
            int sn = s + 2;
            int tn = (dir == 0) ? sn : ((sn == T_LEN - 1) ? (T_LEN - 1) : (T_LEN - 2 - sn));
            rnxt = myrows[tn];
        }

        const float4* __restrict__ h4 = (const float4*)lds_h;
        float4 acc = {0.f, 0.f, 0.f, 0.f};

        // ---- FMA1: 32 own-half rows (h local since end of prev step) ----
        {
            const int hb = (ownbase >> 2) + (q << 3);
#pragma unroll
            for (int r8 = 0; r8 < 8; r8++) {
                float4 hv = h4[hb + r8];                 // uniform -> broadcast
#pragma unroll
                for (int e = 0; e < 4; e++) {
                    float hs = (e == 0) ? hv.x : (e == 1) ? hv.y : (e == 2) ? hv.z : hv.w;
                    const int i = 4 * r8 + e;
                    float4 w = (i < 8) ? Wlds[i * 512 + tid] : Wreg[i - 8];
                    acc.x += hs * w.x; acc.y += hs * w.y; acc.z += hs * w.z; acc.w += hs * w.w;
                }
            }
        }
        // ---- resolve partner h: tag-check (usually passes 1st try) ----
        if (s > 0 && tid < 256) {
            while ((unsigned)(pvbits >> 32) != (unsigned)s)
                pvbits = LOAD_RLX64(&hbpt[((s - 1) & 1) * 256 + tid]);
            lds_h[pbase + tid] = __uint_as_float((unsigned)pvbits);
        }
        BAR_LDS();                                     // A: partner half visible

        // ---- FMA2: 32 partner-half rows ----
        {
            const int hb = (pbase >> 2) + (q << 3);
#pragma unroll
            for (int r8 = 0; r8 < 8; r8++) {
                float4 hv = h4[hb + r8];
#pragma unroll
                for (int e = 0; e < 4; e++) {
                    float hs = (e == 0) ? hv.x : (e == 1) ? hv.y : (e == 2) ? hv.z : hv.w;
                    const int i = 4 * r8 + e;
                    float4 w = (i < 8) ? Wlds[(8 + i) * 512 + tid] : Wreg[24 + i - 8];
                    acc.x += hs * w.x; acc.y += hs * w.y; acc.z += hs * w.z; acc.w += hs * w.w;
                }
            }
        }
        *(float4*)&pr[q * 264 + 4 * (tid & 63)] = acc; // contiguous f4, conflict-free
        BAR_LDS();                                     // B: partials visible

        // ---- reduce 8 wave-partials, tanh, publish (tid<256: col = tid) ----
        if (tid < 256) {
            float p0 = pr[0 * 264 + tid], p1 = pr[1 * 264 + tid];
            float p2 = pr[2 * 264 + tid], p3 = pr[3 * 264 + tid];
            float p4 = pr[4 * 264 + tid], p5 = pr[5 * 264 + tid];
            float p6 = pr[6 * 264 + tid], p7 = pr[7 * 264 + tid];
            float sum = ((p0 + p1) + (p2 + p3)) + ((p4 + p5) + (p6 + p7));
            float z = xv + sum;
            z = fminf(15.f, fmaxf(-15.f, z));
            float e2 = __expf(2.f * z);
            float h1 = 1.f - 2.f / (e2 + 1.f);         // tanh(z)
            xv = xv_next;

            int tphys = (dir == 0) ? s : ((s == T_LEN - 1) ? (T_LEN - 1) : (T_LEN - 2 - s));
            prev_addr = (size_t)tphys * (G_N * 1024) + outbase;
            h_prev = h1;
            if (s < T_LEN - 1) {
                // tagged 8B publish: fire-and-forget, store IS the signal
                unsigned long long pk =
                    ((unsigned long long)(unsigned)(s + 1) << 32) | __float_as_uint(h1);
                STORE_RLX64(&hbme[(s & 1) * 256 + tid], pk);
                lds_h[ownbase + tid] = h1;             // own half stays local
            }
        }
        if (s == T_LEN - 1) break;
        BAR_LDS();                                     // C: own-half h visible
    }
    if (tid < 256) {
        __builtin_nontemporal_store(h_prev, &out[prev_addr]);
        __builtin_nontemporal_store(h_prev, &out[(size_t)T_LEN * (G_N * 1024) + outbase]);
    }
}

extern "C" void kernel_launch(void* const* d_in, const int* in_sizes, int n_in,
                              void* d_out, int out_size, void* d_ws, size_t ws_size,
                              hipStream_t stream) {
    const float* seq   = (const float*)d_in[0];
    const int*   perms = (const int*)d_in[1];
    const float* We    = (const float*)d_in[2];
    const float* Wx    = (const float*)d_in[3];
    const float* Wh    = (const float*)d_in[4];
    const float* b     = (const float*)d_in[5];
    float* out = (float*)d_out;
    char* ws = (char*)d_ws;

    int*   tokens = (int*)(ws + TOK_OFF);
    int*   rows   = (int*)(ws + ROWS_OFF);
    unsigned long long* hbuf = (unsigned long long*)(ws + HBUF_OFF);
    float* P      = (float*)(ws + P_OFF);

    // zero the tag buffer每 launch: stale tags (prev replay) must never match
    (void)hipMemsetAsync(hbuf, 0, NCL * 2 * 2 * 256 * sizeof(unsigned long long), stream);
    tok_kernel<<<512, 256, 0, stream>>>(seq, tokens);
    rows_kernel<<<(G_N * T_LEN + 255) / 256, 256, 0, stream>>>(tokens, perms, rows);
    pgemm_kernel<<<256, 256, 0, stream>>>(We, Wx, b, P);
    rnn_pair<<<NBLK, 512, 0, stream>>>(P, Wh, rows, hbuf, out);
}